// Round 1
// baseline (688.629 us; speedup 1.0000x reference)
//
#include <hip/hip_runtime.h>

#define NVOX (256*256*32)   // 2,097,152
#define CC 64
#define HH 480
#define WW 640
#define HWTOT (HH*WW)        // 307,200 pixels

typedef float vfloat4 __attribute__((ext_vector_type(4)));
typedef int   vint4   __attribute__((ext_vector_type(4)));
typedef int   vint2   __attribute__((ext_vector_type(2)));

// ---------------- Kernel 1: transpose x2d (C,H*W) -> xT (H*W, C), float4 both sides ----
// 64x64 f32 tile per block. Loads: wave reads 16B/lane contiguous (1KB/instr).
// Stores: wave writes 1KB contiguous ((p0+p)*64 rows are adjacent).
// LDS pitch 65 words: scalar access bank = (c + 4*pg + j) % 32 -> 2-way (free, m136).
__global__ __launch_bounds__(256) void transpose_kernel(
    const float* __restrict__ x2d,   // (C, HWTOT)
    float*       __restrict__ xT)    // (HWTOT, C)
{
    __shared__ float tile[64][65];
    int t  = threadIdx.x;
    int p0 = blockIdx.x * 64;

#pragma unroll
    for (int k = 0; k < 4; ++k) {
        int idx = k * 256 + t;
        int c   = idx >> 4;          // 0..63
        int pg  = idx & 15;          // float4 group within the 64-pixel tile
        vfloat4 v = __builtin_nontemporal_load(
            (const vfloat4*)(x2d + (long)c * HWTOT + p0) + pg);
        tile[c][pg*4+0] = v.x;
        tile[c][pg*4+1] = v.y;
        tile[c][pg*4+2] = v.z;
        tile[c][pg*4+3] = v.w;
    }
    __syncthreads();
#pragma unroll
    for (int k = 0; k < 4; ++k) {
        int idx = k * 256 + t;
        int p   = idx >> 4;          // 0..63
        int cg  = idx & 15;          // float4 group of channels
        vfloat4 v;
        v.x = tile[cg*4+0][p];
        v.y = tile[cg*4+1][p];
        v.z = tile[cg*4+2][p];
        v.w = tile[cg*4+3][p];
        // xT re-read immediately by gather: NORMAL store (keep L3-resident)
        ((vfloat4*)(xT + (long)(p0 + p) * CC))[cg] = v;
    }
}

// ---------------- Kernel 2: fused weight + contiguous 64-channel gather ----------------
// One thread per voxel. Weight math inlined (kills the feat/w metadata round-trip).
// Reads: 16B/lane pp+mask+z (coalesced) + depth gather (1.2MB, L2-resident)
//        + 16 x float4 contiguous from xT (256B/voxel block, 4 full lines).
// Writes: 64 nt scalar stores; per wave-instr 64 lanes hit consecutive voxels
//         of one channel plane = 256B contiguous.
__global__ __launch_bounds__(256) void gather_fused_kernel(
    const float* __restrict__ xT,      // (HWTOT, 64)
    const int*   __restrict__ pp,      // (N,2)
    const int*   __restrict__ scale_p, // scalar
    const int*   __restrict__ mask,    // (N,)
    const float* __restrict__ pix_z,   // (N,)
    const float* __restrict__ depth,   // (H*W,)
    float*       __restrict__ out)     // (C, N)
{
    int i = blockIdx.x * blockDim.x + threadIdx.x;   // voxel index
    int scale = scale_p[0];

    vint2 p2 = __builtin_nontemporal_load((const vint2*)pp + i);
    int   m  = __builtin_nontemporal_load(mask + i);
    float z  = __builtin_nontemporal_load(pix_z + i);

    int px = p2.x, py = p2.y;
    int sx = px, sy = py;
    if (scale != 1) { sx = px / scale; sy = py / scale; }
    bool fov = (m != 0);
    int  fi  = fov ? (sy * WW + sx) : 0;   // masked lanes gather addr 0 (broadcast)
    float d  = fov ? depth[py * WW + px] : 0.0f;   // depth table L2-resident
    float diff = z - d;
    float gw = __expf(-0.5f * diff * diff);
    float w  = (d == 0.0f) ? 1.0f : gw;
    w = fov ? w : 0.0f;

    const vfloat4* src = (const vfloat4*)(xT + (long)fi * CC);  // 256B block
    float* op = out + i;

#pragma unroll
    for (int g = 0; g < 16; ++g) {
        vfloat4 v = src[g];
        v.x *= w; v.y *= w; v.z *= w; v.w *= w;
        __builtin_nontemporal_store(v.x, op + (long)(4*g + 0) * NVOX);
        __builtin_nontemporal_store(v.y, op + (long)(4*g + 1) * NVOX);
        __builtin_nontemporal_store(v.z, op + (long)(4*g + 2) * NVOX);
        __builtin_nontemporal_store(v.w, op + (long)(4*g + 3) * NVOX);
    }
}

// ---------------- Fallback (tiny workspace): fully fused, 4 voxels x 4 channels ----------
__global__ __launch_bounds__(256) void fused_kernel(
    const float* __restrict__ x2d,
    const int*   __restrict__ pp,
    const int*   __restrict__ scale_p,
    const int*   __restrict__ mask,
    const float* __restrict__ pix_z,
    const float* __restrict__ depth,
    float*       __restrict__ out)
{
    int t = blockIdx.x * blockDim.x + threadIdx.x;
    long i0 = (long)t * 4;
    int cg = blockIdx.y * 4;
    int scale = scale_p[0];

    vint4 pp0 = ((const vint4*)pp)[t*2+0];
    vint4 pp1 = ((const vint4*)pp)[t*2+1];
    vint4 m4  = ((const vint4*)mask)[t];
    vfloat4 z4 = ((const vfloat4*)pix_z)[t];

    int   px[4] = {pp0.x, pp0.z, pp1.x, pp1.z};
    int   py[4] = {pp0.y, pp0.w, pp1.y, pp1.w};
    int   mm[4] = {m4.x, m4.y, m4.z, m4.w};
    float zz[4] = {z4.x, z4.y, z4.z, z4.w};

    int fi[4]; float wv[4];
#pragma unroll
    for (int j = 0; j < 4; ++j) {
        int sx = px[j], sy = py[j];
        if (scale != 1) { sx = px[j] / scale; sy = py[j] / scale; }
        int feat = sy * WW + sx;
        bool fov = (mm[j] != 0);
        float d = fov ? depth[py[j] * WW + px[j]] : 0.0f;
        float diff = zz[j] - d;
        float gw = __expf(-0.5f * diff * diff);
        float w = (d == 0.0f) ? 1.0f : gw;
        wv[j] = fov ? w : 0.0f;
        fi[j] = fov ? feat : 0;
    }

#pragma unroll
    for (int g = 0; g < 4; ++g) {
        int c = cg + g;
        const float* base = x2d + (long)c * HWTOT;
        vfloat4 v;
        v.x = base[fi[0]] * wv[0];
        v.y = base[fi[1]] * wv[1];
        v.z = base[fi[2]] * wv[2];
        v.w = base[fi[3]] * wv[3];
        __builtin_nontemporal_store(v, (vfloat4*)(out + (long)c * NVOX + i0));
    }
}

extern "C" void kernel_launch(void* const* d_in, const int* in_sizes, int n_in,
                              void* d_out, int out_size, void* d_ws, size_t ws_size,
                              hipStream_t stream) {
    const float* x2d     = (const float*)d_in[0];
    const int*   pp      = (const int*)d_in[1];
    const int*   scale_p = (const int*)d_in[2];
    const int*   mask    = (const int*)d_in[3];
    const float* pix_z   = (const float*)d_in[4];
    const float* depth   = (const float*)d_in[5];
    float*       out     = (float*)d_out;

    dim3 blk(256);
    size_t need_xT = (size_t)HWTOT * CC * 4;   // 78.6 MB

    if (ws_size >= need_xT) {
        float* xT = (float*)d_ws;
        transpose_kernel<<<dim3(HWTOT/64), blk, 0, stream>>>(x2d, xT);
        gather_fused_kernel<<<dim3(NVOX/256), blk, 0, stream>>>(xT, pp, scale_p,
                                                                mask, pix_z, depth, out);
    } else {
        fused_kernel<<<dim3(NVOX/4/256, CC/4), blk, 0, stream>>>(x2d, pp, scale_p,
                                                                 mask, pix_z, depth, out);
    }
}

// Round 2
// 673.142 us; speedup vs baseline: 1.0230x; 1.0230x over previous
//
#include <hip/hip_runtime.h>

#define NVOX (256*256*32)   // 2,097,152
#define CC 64
#define HH 480
#define WW 640
#define HWTOT (HH*WW)        // 307,200 pixels

typedef float vfloat4 __attribute__((ext_vector_type(4)));
typedef int   vint4   __attribute__((ext_vector_type(4)));
typedef int   vint2   __attribute__((ext_vector_type(2)));
typedef _Float16 f16x4 __attribute__((ext_vector_type(4)));
typedef _Float16 f16x8 __attribute__((ext_vector_type(8)));

// ---------------- Kernel 1: transpose + downconvert x2d (C,HW) f32 -> xT (HW, C) fp16 ----
// 64x64 f32 tile per block. Loads: 16B/lane contiguous (1KB/wave-instr, NT: read-once).
// Stores: f16x4 per thread, wave = 4 consecutive 128B rows = 512B contiguous.
// LDS pitch 65 words -> worst 2-way bank aliasing (free, m136).
__global__ __launch_bounds__(256) void transpose_f16_kernel(
    const float* __restrict__ x2d,   // (C, HWTOT) f32
    _Float16*    __restrict__ xT)    // (HWTOT, C) fp16
{
    __shared__ float tile[64][65];
    int t  = threadIdx.x;
    int p0 = blockIdx.x * 64;

#pragma unroll
    for (int k = 0; k < 4; ++k) {
        int idx = k * 256 + t;
        int c   = idx >> 4;          // 0..63 channel
        int pg  = idx & 15;          // float4 group within 64-pixel tile
        vfloat4 v = __builtin_nontemporal_load(
            (const vfloat4*)(x2d + (long)c * HWTOT + p0) + pg);
        tile[c][pg*4+0] = v.x;
        tile[c][pg*4+1] = v.y;
        tile[c][pg*4+2] = v.z;
        tile[c][pg*4+3] = v.w;
    }
    __syncthreads();
#pragma unroll
    for (int k = 0; k < 4; ++k) {
        int idx = k * 256 + t;
        int p   = idx >> 4;          // 0..63 pixel within tile
        int cg  = idx & 15;          // f16x4 channel group
        f16x4 h;
        h[0] = (_Float16)tile[cg*4+0][p];
        h[1] = (_Float16)tile[cg*4+1][p];
        h[2] = (_Float16)tile[cg*4+2][p];
        h[3] = (_Float16)tile[cg*4+3][p];
        // xT re-read immediately by gather: NORMAL store (keep cache-resident)
        ((f16x4*)(xT + (long)(p0 + p) * CC))[cg] = h;
    }
}

__device__ __forceinline__ void emit8(float* op, f16x8 v, float w, int c0) {
#pragma unroll
    for (int j = 0; j < 8; ++j) {
        float f = (float)v[j] * w;
        __builtin_nontemporal_store(f, op + (long)(c0 + j) * NVOX);
    }
}

// ---------------- Kernel 2: fused weight + contiguous 64-channel fp16 gather ------------
// One thread per voxel. Row = 128B = 8 x b128 loads, all issued before any use
// (32 payload VGPRs -> total ~60, stays under the 64-VGPR occupancy cliff).
// Writes: 64 nt scalar stores; per wave-instr 64 lanes = 256B contiguous in one plane.
__global__ __launch_bounds__(256) void gather_f16_kernel(
    const _Float16* __restrict__ xT,      // (HWTOT, 64) fp16
    const int*      __restrict__ pp,      // (N,2)
    const int*      __restrict__ scale_p, // scalar
    const int*      __restrict__ mask,    // (N,)
    const float*    __restrict__ pix_z,   // (N,)
    const float*    __restrict__ depth,   // (H*W,) f32, L2-resident (1.2MB)
    float*          __restrict__ out)     // (C, N) f32
{
    int i = blockIdx.x * blockDim.x + threadIdx.x;   // voxel index
    int scale = scale_p[0];

    vint2 p2 = __builtin_nontemporal_load((const vint2*)pp + i);
    int   m  = __builtin_nontemporal_load(mask + i);
    float z  = __builtin_nontemporal_load(pix_z + i);

    int px = p2.x, py = p2.y;
    int sx = px, sy = py;
    if (scale != 1) { sx = px / scale; sy = py / scale; }
    bool fov = (m != 0);
    int  fi  = fov ? (sy * WW + sx) : 0;   // masked lanes gather row 0 (broadcast)
    float d  = fov ? depth[py * WW + px] : 0.0f;
    float diff = z - d;
    float gw = __expf(-0.5f * diff * diff);
    float w  = (d == 0.0f) ? 1.0f : gw;
    w = fov ? w : 0.0f;

    const f16x8* src = (const f16x8*)(xT + (long)fi * CC);  // 128B-aligned row
    float* op = out + i;

    // issue all 8 gather loads up front -> max memory-level parallelism
    f16x8 s0 = src[0], s1 = src[1], s2 = src[2], s3 = src[3];
    f16x8 s4 = src[4], s5 = src[5], s6 = src[6], s7 = src[7];

    emit8(op, s0,  w,  0);
    emit8(op, s1,  w,  8);
    emit8(op, s2,  w, 16);
    emit8(op, s3,  w, 24);
    emit8(op, s4,  w, 32);
    emit8(op, s5,  w, 40);
    emit8(op, s6,  w, 48);
    emit8(op, s7,  w, 56);
}

// ---------------- Fallback (tiny workspace): fully fused f32, 4 voxels x 4 channels -----
__global__ __launch_bounds__(256) void fused_kernel(
    const float* __restrict__ x2d,
    const int*   __restrict__ pp,
    const int*   __restrict__ scale_p,
    const int*   __restrict__ mask,
    const float* __restrict__ pix_z,
    const float* __restrict__ depth,
    float*       __restrict__ out)
{
    int t = blockIdx.x * blockDim.x + threadIdx.x;
    long i0 = (long)t * 4;
    int cg = blockIdx.y * 4;
    int scale = scale_p[0];

    vint4 pp0 = ((const vint4*)pp)[t*2+0];
    vint4 pp1 = ((const vint4*)pp)[t*2+1];
    vint4 m4  = ((const vint4*)mask)[t];
    vfloat4 z4 = ((const vfloat4*)pix_z)[t];

    int   px[4] = {pp0.x, pp0.z, pp1.x, pp1.z};
    int   py[4] = {pp0.y, pp0.w, pp1.y, pp1.w};
    int   mm[4] = {m4.x, m4.y, m4.z, m4.w};
    float zz[4] = {z4.x, z4.y, z4.z, z4.w};

    int fi[4]; float wv[4];
#pragma unroll
    for (int j = 0; j < 4; ++j) {
        int sx = px[j], sy = py[j];
        if (scale != 1) { sx = px[j] / scale; sy = py[j] / scale; }
        int feat = sy * WW + sx;
        bool fov = (mm[j] != 0);
        float d = fov ? depth[py[j] * WW + px[j]] : 0.0f;
        float diff = zz[j] - d;
        float gw = __expf(-0.5f * diff * diff);
        float w = (d == 0.0f) ? 1.0f : gw;
        wv[j] = fov ? w : 0.0f;
        fi[j] = fov ? feat : 0;
    }

#pragma unroll
    for (int g = 0; g < 4; ++g) {
        int c = cg + g;
        const float* base = x2d + (long)c * HWTOT;
        vfloat4 v;
        v.x = base[fi[0]] * wv[0];
        v.y = base[fi[1]] * wv[1];
        v.z = base[fi[2]] * wv[2];
        v.w = base[fi[3]] * wv[3];
        __builtin_nontemporal_store(v, (vfloat4*)(out + (long)c * NVOX + i0));
    }
}

extern "C" void kernel_launch(void* const* d_in, const int* in_sizes, int n_in,
                              void* d_out, int out_size, void* d_ws, size_t ws_size,
                              hipStream_t stream) {
    const float* x2d     = (const float*)d_in[0];
    const int*   pp      = (const int*)d_in[1];
    const int*   scale_p = (const int*)d_in[2];
    const int*   mask    = (const int*)d_in[3];
    const float* pix_z   = (const float*)d_in[4];
    const float* depth   = (const float*)d_in[5];
    float*       out     = (float*)d_out;

    dim3 blk(256);
    size_t need_xT = (size_t)HWTOT * CC * sizeof(_Float16);   // 39.3 MB

    if (ws_size >= need_xT) {
        _Float16* xT = (_Float16*)d_ws;
        transpose_f16_kernel<<<dim3(HWTOT/64), blk, 0, stream>>>(x2d, xT);
        gather_f16_kernel<<<dim3(NVOX/256), blk, 0, stream>>>(xT, pp, scale_p,
                                                              mask, pix_z, depth, out);
    } else {
        fused_kernel<<<dim3(NVOX/4/256, CC/4), blk, 0, stream>>>(x2d, pp, scale_p,
                                                                 mask, pix_z, depth, out);
    }
}